// Round 2
// baseline (1352.208 us; speedup 1.0000x reference)
//
#include <hip/hip_runtime.h>
#include <math.h>

#define B_    2
#define C_    256
#define NH    8
#define HD    32
#define P_    1024
#define T_    8
#define QQ    8192          // T_*P_
#define SCALE 0.0625f       // 1/sqrt(256)

// LDS strides (in floats). Head stride padded 32->36 so different heads land in
// different banks (n*32 dwords === 0 mod 32 banks otherwise); row stride 8*36+4.
#define HS 36
#define RS 292
#define ES 132              // e_s row stride (16q*8n=128 +4)

// ---------------------------------------------------------------------------
// Projection GEMM: out[b][pos][o] = sum_c in[b][c][pos] * W[o][c] + bias[o]
// in is channel-major (c stride = npos), out is pos-major with o contiguous.
// 64pos x 64o tile, 256 threads, 4x4 micro-tile, K-chunk 16.
// ---------------------------------------------------------------------------
__global__ __launch_bounds__(256) void k_proj(
    const float* __restrict__ in, const float* __restrict__ W,
    const float* __restrict__ bias, float* __restrict__ out, int npos)
{
    __shared__ float In_s[16][68];
    __shared__ float W_s[16][68];
    const int t    = threadIdx.x;
    const int pos0 = blockIdx.x * 64;
    const int o0   = blockIdx.y * 64;
    const int b    = blockIdx.z;
    const float* inb = in + (size_t)b * C_ * npos;

    const int ty = t >> 4, tx = t & 15;
    float acc[4][4] = {};

    for (int c0 = 0; c0 < C_; c0 += 16) {
        __syncthreads();
        {
            const int ct = t >> 4;            // 0..15  (c row)
            const int px = (t & 15) << 2;     // 0..60
            *reinterpret_cast<float4*>(&In_s[ct][px]) =
                *reinterpret_cast<const float4*>(inb + (size_t)(c0 + ct) * npos + pos0 + px);
            const int oo = t >> 2;            // 0..63
            const int c4 = (t & 3) << 2;      // 0..12
            float4 wv = *reinterpret_cast<const float4*>(W + (size_t)(o0 + oo) * C_ + c0 + c4);
            W_s[c4 + 0][oo] = wv.x;
            W_s[c4 + 1][oo] = wv.y;
            W_s[c4 + 2][oo] = wv.z;
            W_s[c4 + 3][oo] = wv.w;
        }
        __syncthreads();
#pragma unroll
        for (int cc = 0; cc < 16; ++cc) {
            float4 av = *reinterpret_cast<const float4*>(&In_s[cc][ty << 2]);
            float4 bv = *reinterpret_cast<const float4*>(&W_s[cc][tx << 2]);
            float a[4] = {av.x, av.y, av.z, av.w};
            float w[4] = {bv.x, bv.y, bv.z, bv.w};
#pragma unroll
            for (int i = 0; i < 4; ++i)
#pragma unroll
                for (int j = 0; j < 4; ++j)
                    acc[i][j] += a[i] * w[j];
        }
    }
    const float4 bo4 = *reinterpret_cast<const float4*>(bias + o0 + (tx << 2));
    const float bb[4] = {bo4.x, bo4.y, bo4.z, bo4.w};
#pragma unroll
    for (int i = 0; i < 4; ++i) {
        const int pos = pos0 + (ty << 2) + i;
        float4 v = make_float4(acc[i][0] + bb[0], acc[i][1] + bb[1],
                               acc[i][2] + bb[2], acc[i][3] + bb[3]);
        *reinterpret_cast<float4*>(out + ((size_t)b * npos + pos) * C_ + o0 + (tx << 2)) = v;
    }
}

// ---------------------------------------------------------------------------
// Pass 1: softmax denominators. Block = (ptile of 16 p, qblock of 1024 q, b).
// Computes sum_q exp(scale * Q.K) for its q-range, atomicAdd into sums[b][p][n].
// ---------------------------------------------------------------------------
__global__ __launch_bounds__(256, 2) void k_pass1(
    const float* __restrict__ Qp, const float* __restrict__ Kp,
    float* __restrict__ sums)
{
    __shared__ float Q_s[16 * RS];
    __shared__ float K_s[32 * RS];
    __shared__ float red[8][16][NH];
    const int t   = threadIdx.x;
    const int p0  = blockIdx.x * 16;
    const int qb0 = blockIdx.y * 1024;
    const int b   = blockIdx.z;
    const float* Qb = Qp + ((size_t)b * P_ + p0) * C_;
    const float* Kb = Kp + ((size_t)b * QQ + qb0) * C_;

#pragma unroll
    for (int k = 0; k < 4; ++k) {                // Q tile: 16 x 256
        int idx = t + 256 * k;                   // float4 index 0..1023
        int row = idx >> 6;
        int c   = (idx & 63) << 2;
        float4 v = *reinterpret_cast<const float4*>(Qb + (size_t)row * C_ + c);
        *reinterpret_cast<float4*>(&Q_s[row * RS + (c >> 5) * HS + (c & 31)]) = v;
    }

    const int n  = t & 7;
    const int pg = (t >> 3) & 3;
    const int qg = t >> 5;                       // 0..7
    float sumloc[4] = {0.f, 0.f, 0.f, 0.f};

    for (int ch = 0; ch < 32; ++ch) {
        __syncthreads();
#pragma unroll
        for (int k = 0; k < 8; ++k) {            // K chunk: 32 x 256
            int idx = t + 256 * k;
            int row = idx >> 6;
            int c   = (idx & 63) << 2;
            float4 v = *reinterpret_cast<const float4*>(Kb + (size_t)(ch * 32 + row) * C_ + c);
            *reinterpret_cast<float4*>(&K_s[row * RS + (c >> 5) * HS + (c & 31)]) = v;
        }
        __syncthreads();
        float s[4][4] = {};
#pragma unroll
        for (int d0 = 0; d0 < 32; d0 += 4) {
            float4 kv[4], qv[4];
#pragma unroll
            for (int j = 0; j < 4; ++j)
                kv[j] = *reinterpret_cast<const float4*>(&K_s[(qg * 4 + j) * RS + n * HS + d0]);
#pragma unroll
            for (int i = 0; i < 4; ++i)
                qv[i] = *reinterpret_cast<const float4*>(&Q_s[(pg * 4 + i) * RS + n * HS + d0]);
#pragma unroll
            for (int i = 0; i < 4; ++i)
#pragma unroll
                for (int j = 0; j < 4; ++j)
                    s[i][j] += kv[j].x * qv[i].x + kv[j].y * qv[i].y +
                               kv[j].z * qv[i].z + kv[j].w * qv[i].w;
        }
#pragma unroll
        for (int i = 0; i < 4; ++i)
#pragma unroll
            for (int j = 0; j < 4; ++j)
                sumloc[i] += __expf(s[i][j] * SCALE);
    }
#pragma unroll
    for (int i = 0; i < 4; ++i)
        red[qg][pg * 4 + i][n] = sumloc[i];
    __syncthreads();
    if (t < 128) {
        int p = t & 15, nn = t >> 4;
        float tot = 0.f;
#pragma unroll
        for (int g = 0; g < 8; ++g) tot += red[g][p][nn];
        atomicAdd(&sums[((size_t)b * P_ + p0 + p) * NH + nn], tot);
    }
}

// ---------------------------------------------------------------------------
// Pass 2: recompute energy, write normalized A (coalesced via LDS staging with
// all 8 heads per block), accumulate PV partials per q-block.
// Block = (ptile 16, qblock 1024, b); q-chunk 16.
// ---------------------------------------------------------------------------
__global__ __launch_bounds__(256, 2) void k_pass2(
    const float* __restrict__ Qp, const float* __restrict__ Kp,
    const float* __restrict__ Vp, const float* __restrict__ sums,
    float* __restrict__ Aout, float* __restrict__ partials)
{
    __shared__ float Q_s[16 * RS];
    __shared__ float K_s[16 * RS];
    __shared__ float V_s[16 * RS];
    __shared__ float e_s[16 * ES];
    __shared__ float invs[16][NH];
    const int t    = threadIdx.x;
    const int p0   = blockIdx.x * 16;
    const int qblk = blockIdx.y;
    const int qb0  = qblk * 1024;
    const int b    = blockIdx.z;
    const float* Qb = Qp + ((size_t)b * P_ + p0) * C_;
    const float* Kb = Kp + ((size_t)b * QQ + qb0) * C_;
    const float* Vb = Vp + ((size_t)b * QQ + qb0) * C_;

#pragma unroll
    for (int k = 0; k < 4; ++k) {                // Q tile
        int idx = t + 256 * k;
        int row = idx >> 6;
        int c   = (idx & 63) << 2;
        float4 v = *reinterpret_cast<const float4*>(Qb + (size_t)row * C_ + c);
        *reinterpret_cast<float4*>(&Q_s[row * RS + (c >> 5) * HS + (c & 31)]) = v;
    }
    if (t < 128) {
        int p = t & 15, nn = t >> 4;
        invs[p][nn] = 1.0f / sums[((size_t)b * P_ + p0 + p) * NH + nn];
    }

    const int n   = t & 7;
    const int pg  = (t >> 3) & 3;
    const int qg  = t >> 5;                      // 0..7 -> q pair base qg*2
    const int cv0 = (t & 31) << 3;               // PV: c base (8 wide)
    const int pv0 = (t >> 5) << 1;               // PV: p row pair
    const int nv  = cv0 >> 5, dv = cv0 & 31;
    float acc[2][8] = {};

    float* Arow = Aout + (((size_t)b * P_ + p0) * QQ + qb0) * NH;

    for (int ch = 0; ch < 64; ++ch) {
        __syncthreads();
#pragma unroll
        for (int k = 0; k < 4; ++k) {            // K+V chunk: 16 x 256 each
            int idx = t + 256 * k;
            int row = idx >> 6;
            int c   = (idx & 63) << 2;
            int ld  = row * RS + (c >> 5) * HS + (c & 31);
            *reinterpret_cast<float4*>(&K_s[ld]) =
                *reinterpret_cast<const float4*>(Kb + (size_t)(ch * 16 + row) * C_ + c);
            *reinterpret_cast<float4*>(&V_s[ld]) =
                *reinterpret_cast<const float4*>(Vb + (size_t)(ch * 16 + row) * C_ + c);
        }
        __syncthreads();
        // scores: [4p x 2q] per thread
        float s[4][2] = {};
#pragma unroll
        for (int d0 = 0; d0 < 32; d0 += 4) {
            float4 kv[2], qv[4];
#pragma unroll
            for (int j = 0; j < 2; ++j)
                kv[j] = *reinterpret_cast<const float4*>(&K_s[(qg * 2 + j) * RS + n * HS + d0]);
#pragma unroll
            for (int i = 0; i < 4; ++i)
                qv[i] = *reinterpret_cast<const float4*>(&Q_s[(pg * 4 + i) * RS + n * HS + d0]);
#pragma unroll
            for (int i = 0; i < 4; ++i)
#pragma unroll
                for (int j = 0; j < 2; ++j)
                    s[i][j] += kv[j].x * qv[i].x + kv[j].y * qv[i].y +
                               kv[j].z * qv[i].z + kv[j].w * qv[i].w;
        }
#pragma unroll
        for (int i = 0; i < 4; ++i)
#pragma unroll
            for (int j = 0; j < 2; ++j) {
                float e = __expf(s[i][j] * SCALE) * invs[pg * 4 + i][n];
                e_s[(pg * 4 + i) * ES + (qg * 2 + j) * NH + n] = e;
            }
        __syncthreads();
        // coalesced A write: 16 rows x 128 contiguous floats
        {
            int row = t >> 4;                    // 0..15
            int col = (t & 15) << 3;             // 0..120
            float4 v0 = *reinterpret_cast<const float4*>(&e_s[row * ES + col]);
            float4 v1 = *reinterpret_cast<const float4*>(&e_s[row * ES + col + 4]);
            float* dst = Arow + (size_t)row * QQ * NH + (size_t)ch * 16 * NH + col;
            *reinterpret_cast<float4*>(dst)     = v0;
            *reinterpret_cast<float4*>(dst + 4) = v1;
        }
        // PV accumulate: thread owns [2p x 8c]
#pragma unroll
        for (int q = 0; q < 16; ++q) {
            float e0 = e_s[pv0 * ES + q * NH + nv];
            float e1 = e_s[(pv0 + 1) * ES + q * NH + nv];
            float4 v0 = *reinterpret_cast<const float4*>(&V_s[q * RS + nv * HS + dv]);
            float4 v1 = *reinterpret_cast<const float4*>(&V_s[q * RS + nv * HS + dv + 4]);
            float vv[8] = {v0.x, v0.y, v0.z, v0.w, v1.x, v1.y, v1.z, v1.w};
#pragma unroll
            for (int kk = 0; kk < 8; ++kk) {
                acc[0][kk] += e0 * vv[kk];
                acc[1][kk] += e1 * vv[kk];
            }
        }
    }
    // store PV partials (exclusive ownership, no atomics)
    float* pp = partials + (((size_t)(qblk * B_ + b) * P_ + p0 + pv0) * C_) + cv0;
    *reinterpret_cast<float4*>(pp)          = make_float4(acc[0][0], acc[0][1], acc[0][2], acc[0][3]);
    *reinterpret_cast<float4*>(pp + 4)      = make_float4(acc[0][4], acc[0][5], acc[0][6], acc[0][7]);
    *reinterpret_cast<float4*>(pp + C_)     = make_float4(acc[1][0], acc[1][1], acc[1][2], acc[1][3]);
    *reinterpret_cast<float4*>(pp + C_ + 4) = make_float4(acc[1][4], acc[1][5], acc[1][6], acc[1][7]);
}

// ---------------------------------------------------------------------------
// Reduce the 8 per-qblock PV partials -> outp[b][p][c]
// ---------------------------------------------------------------------------
__global__ void k_reduce(const float* __restrict__ partials, float* __restrict__ outp)
{
    int g = blockIdx.x * blockDim.x + threadIdx.x;   // float4 index, 131072 total
    int b = g >> 16;
    int x = g & 65535;
    float4 s = make_float4(0.f, 0.f, 0.f, 0.f);
#pragma unroll
    for (int qb = 0; qb < 8; ++qb) {
        float4 v = reinterpret_cast<const float4*>(partials)[(size_t)(qb * B_ + b) * 65536 + x];
        s.x += v.x; s.y += v.y; s.z += v.z; s.w += v.w;
    }
    reinterpret_cast<float4*>(outp)[g] = s;
}

// ---------------------------------------------------------------------------
// Output projection: out[b][o][p] = sum_c Wo[o][c]*outp[b][p][c] + bo[o]
// Both operands row-major in c -> transpose on LDS store.
// ---------------------------------------------------------------------------
__global__ __launch_bounds__(256) void k_outproj(
    const float* __restrict__ outp, const float* __restrict__ Wo,
    const float* __restrict__ bo, float* __restrict__ out)
{
    __shared__ float P_sT[16][68];
    __shared__ float W_sT[16][68];
    const int t   = threadIdx.x;
    const int pt0 = blockIdx.x * 64;
    const int o0  = blockIdx.y * 64;
    const int b   = blockIdx.z;
    const int ty = t >> 4, tx = t & 15;
    float acc[4][4] = {};

    for (int c0 = 0; c0 < C_; c0 += 16) {
        __syncthreads();
        {
            int pr = t >> 2;                 // 0..63
            int c4 = (t & 3) << 2;
            float4 v = *reinterpret_cast<const float4*>(outp + ((size_t)b * P_ + pt0 + pr) * C_ + c0 + c4);
            P_sT[c4 + 0][pr] = v.x; P_sT[c4 + 1][pr] = v.y;
            P_sT[c4 + 2][pr] = v.z; P_sT[c4 + 3][pr] = v.w;
            float4 w = *reinterpret_cast<const float4*>(Wo + (size_t)(o0 + pr) * C_ + c0 + c4);
            W_sT[c4 + 0][pr] = w.x; W_sT[c4 + 1][pr] = w.y;
            W_sT[c4 + 2][pr] = w.z; W_sT[c4 + 3][pr] = w.w;
        }
        __syncthreads();
#pragma unroll
        for (int cc = 0; cc < 16; ++cc) {
            float4 wv = *reinterpret_cast<const float4*>(&W_sT[cc][ty << 2]);
            float4 pv = *reinterpret_cast<const float4*>(&P_sT[cc][tx << 2]);
            float w[4] = {wv.x, wv.y, wv.z, wv.w};
            float p[4] = {pv.x, pv.y, pv.z, pv.w};
#pragma unroll
            for (int i = 0; i < 4; ++i)
#pragma unroll
                for (int j = 0; j < 4; ++j)
                    acc[i][j] += w[i] * p[j];
        }
    }
#pragma unroll
    for (int i = 0; i < 4; ++i) {
        int o = o0 + (ty << 2) + i;
        float bias = bo[o];
        float4 v = make_float4(acc[i][0] + bias, acc[i][1] + bias,
                               acc[i][2] + bias, acc[i][3] + bias);
        *reinterpret_cast<float4*>(out + ((size_t)b * C_ + o) * P_ + pt0 + (tx << 2)) = v;
    }
}

// ---------------------------------------------------------------------------
extern "C" void kernel_launch(void* const* d_in, const int* in_sizes, int n_in,
                              void* d_out, int out_size, void* d_ws, size_t ws_size,
                              hipStream_t stream)
{
    (void)in_sizes; (void)n_in; (void)out_size; (void)ws_size;
    const float* query = (const float*)d_in[0];
    const float* key   = (const float*)d_in[1];
    const float* value = (const float*)d_in[2];
    const float* Wq = (const float*)d_in[3];
    const float* bq = (const float*)d_in[4];
    const float* Wk = (const float*)d_in[5];
    const float* bk = (const float*)d_in[6];
    const float* Wv = (const float*)d_in[7];
    const float* bv = (const float*)d_in[8];
    const float* Wo = (const float*)d_in[9];
    const float* bo = (const float*)d_in[10];

    float* out  = (float*)d_out;
    float* Aout = out + (size_t)B_ * C_ * P_;     // A follows `out` in d_out

    // workspace carve-up (floats): 54.6 MB total
    float* ws    = (float*)d_ws;
    float* Qp    = ws;                                  // [B][P][C]    2 MB
    float* Kp    = Qp   + (size_t)B_ * P_ * C_;         // [B][QQ][C]  16 MB
    float* Vp    = Kp   + (size_t)B_ * QQ * C_;         // [B][QQ][C]  16 MB
    float* sums  = Vp   + (size_t)B_ * QQ * C_;         // [B][P][NH]  64 KB
    float* outp  = sums + (size_t)B_ * P_ * NH;         // [B][P][C]    2 MB
    float* parts = outp + (size_t)B_ * P_ * C_;         // [8][B][P][C] 16 MB

    hipMemsetAsync(sums, 0, (size_t)B_ * P_ * NH * sizeof(float), stream);

    k_proj<<<dim3(P_ / 64, 4, B_), 256, 0, stream>>>(query, Wq, bq, Qp, P_);
    k_proj<<<dim3(QQ / 64, 4, B_), 256, 0, stream>>>(key,   Wk, bk, Kp, QQ);
    k_proj<<<dim3(QQ / 64, 4, B_), 256, 0, stream>>>(value, Wv, bv, Vp, QQ);

    k_pass1<<<dim3(64, 8, B_), 256, 0, stream>>>(Qp, Kp, sums);
    k_pass2<<<dim3(64, 8, B_), 256, 0, stream>>>(Qp, Kp, Vp, sums, Aout, parts);

    k_reduce<<<dim3(512), 256, 0, stream>>>(parts, outp);
    k_outproj<<<dim3(P_ / 64, 4, B_), 256, 0, stream>>>(outp, Wo, bo, out);
}